// Round 8
// baseline (482.772 us; speedup 1.0000x reference)
//
#include <hip/hip_runtime.h>

// ---------------------------------------------------------------------------
// SpikingMLP forward. bf16 MFMA GEMMs with split-precision weights
// (W = W_hi + W_lo bf16). R8: W staged to LDS as RAW FP32 via global_load_lds
// DMA (zero staging VALU); hi/lo split at fragment-read time. BK=32,
// double-buffered LDS (48 KB -> 3 blocks/CU), one barrier per K-step.
// bn_stats+bn_if fused. Bit-identical arithmetic to R7 (same spike trains).
// ---------------------------------------------------------------------------

#define T_STEPS 8
#define BATCH 64
#define F0 32768
#define DIM 2048
#define NROWS 512
#define NC 1000

typedef __attribute__((ext_vector_type(8))) short short8;   // 8 bf16
typedef __attribute__((ext_vector_type(4))) float f32x4;    // MFMA acc

__device__ __forceinline__ unsigned short bf16_rne(float f) {
    unsigned int u = __float_as_uint(f);
    u += 0x7FFFu + ((u >> 16) & 1u);
    return (unsigned short)(u >> 16);
}

#define BM 128
#define BN 128
#define BK 32   // K-elems per tile; A row = 64 B, W row = 128 B

__global__ __launch_bounds__(256) void gemm_splitk(
    const unsigned short* __restrict__ A, const float* __restrict__ W,
    float* __restrict__ part, int M, int N, int K, int Kpart, int Wrows)
{
    __shared__ unsigned short As[2][BM * BK];   // 2 x 8 KB, bf16
    __shared__ float          Wf[2][BN * BK];   // 2 x 16 KB, fp32

    // ---- XCD-chunked bijective remap (grid %8==0 at all call sites) ----
    const int gx = gridDim.x, gy = gridDim.y;
    const int nwg = gx * gy * gridDim.z;
    const int lid = blockIdx.x + gx * (blockIdx.y + gy * blockIdx.z);
    const int cpx = nwg >> 3;
    const int nid = (lid & 7) * cpx + (lid >> 3);
    const int bx  = nid % gx;
    const int by  = (nid / gx) % gy;
    const int kz  = nid / (gx * gy);

    const int tid  = threadIdx.x;
    const int lane = tid & 63;
    const int w    = tid >> 6;
    const int bm   = bx * BM;
    const int bn   = by * BN;
    const int ksteps = Kpart / BK;
    const int wm = (w >> 1) * 64;
    const int wn = (w & 1) * 64;

    // Staging: LDS dst linear, global src pre-swizzled (rule 21).
    // A: phys slot p (16B units of 64B row) holds logical p ^ ((row>>1)&3).
    //    For writer lane: row == lane>>2 (mod 8) -> x = (lane>>3)&3.
    // W: phys slot p (of 128B row) holds logical p ^ (row&7).
    //    For writer lane: row == lane>>3 (mod 8) -> x = lane>>3.
    const int aslot = ((lane & 3) ^ ((lane >> 3) & 3)) << 4;
    const int wslot = ((lane & 7) ^ (lane >> 3)) << 4;
    const int arow  = w * 32 + (lane >> 2);   // + 16*c
    const int wrow  = w * 32 + (lane >> 3);   // + 8*c
    const size_t abase = (size_t)(bm + arow) * K;
    const int kbase = kz * Kpart;

    f32x4 acc[4][4] = {};

    auto stage = [&](int buf, int kt) {
        const int k0 = kbase + kt * BK;
#pragma unroll
        for (int c = 0; c < 2; ++c) {
            const char* src = (const char*)A + (abase + (size_t)c * 16 * K + k0) * 2 + aslot;
            __builtin_amdgcn_global_load_lds(
                (const __attribute__((address_space(1))) void*)src,
                (__attribute__((address_space(3))) void*)&As[buf][(w * 32 + c * 16) * BK],
                16, 0, 0);
        }
#pragma unroll
        for (int c = 0; c < 4; ++c) {
            const int rg = min(bn + wrow + c * 8, Wrows - 1);
            const char* src = (const char*)W + ((size_t)rg * K + k0) * 4 + wslot;
            __builtin_amdgcn_global_load_lds(
                (const __attribute__((address_space(1))) void*)src,
                (__attribute__((address_space(3))) void*)&Wf[buf][(w * 32 + c * 8) * BK],
                16, 0, 0);
        }
    };

    stage(0, 0);
    __syncthreads();

    // read-side phys slots (lane-constant since rows are +16*i offsets)
    const int aphys = (((lane >> 4)) ^ ((lane >> 1) & 3)) << 4;
    const int ws0   = (((lane >> 4) * 2)     ^ (lane & 7)) << 4;
    const int ws1   = (((lane >> 4) * 2 + 1) ^ (lane & 7)) << 4;

    int cur = 0;
    for (int kt = 0; kt < ksteps; ++kt) {
        if (kt + 1 < ksteps) stage(cur ^ 1, kt + 1);   // prefetch next tile (DMA only)

        short8 a[4];
#pragma unroll
        for (int mi = 0; mi < 4; ++mi) {
            const int ra = wm + mi * 16 + (lane & 15);
            a[mi] = *(const short8*)((const char*)As[cur] + ra * 64 + aphys);
        }
#pragma unroll
        for (int ni = 0; ni < 4; ++ni) {
            const int rw = wn + ni * 16 + (lane & 15);
            const char* rowp = (const char*)Wf[cur] + rw * 128;
            const float4 w0 = *(const float4*)(rowp + ws0);
            const float4 w1 = *(const float4*)(rowp + ws1);
            const float vf[8] = {w0.x, w0.y, w0.z, w0.w, w1.x, w1.y, w1.z, w1.w};
            short8 bh, bl;
#pragma unroll
            for (int e = 0; e < 8; ++e) {
                const unsigned short h = bf16_rne(vf[e]);
                bh[e] = (short)h;
                bl[e] = (short)bf16_rne(vf[e] - __uint_as_float((unsigned int)h << 16));
            }
#pragma unroll
            for (int mi = 0; mi < 4; ++mi) {
                acc[mi][ni] = __builtin_amdgcn_mfma_f32_16x16x32_bf16(a[mi], bh, acc[mi][ni], 0, 0, 0);
                acc[mi][ni] = __builtin_amdgcn_mfma_f32_16x16x32_bf16(a[mi], bl, acc[mi][ni], 0, 0, 0);
            }
        }
        __syncthreads();   // drains next-tile DMA; all reads of cur done
        cur ^= 1;
    }

    // ---- epilogue: partial store (C/D: col=lane&15, row=(lane>>4)*4+e) ----
    const size_t zoff = (size_t)kz * M * N;
#pragma unroll
    for (int mi = 0; mi < 4; ++mi) {
        const int gr0 = bm + wm + mi * 16 + (lane >> 4) * 4;
#pragma unroll
        for (int ni = 0; ni < 4; ++ni) {
            const int gc = bn + wn + ni * 16 + (lane & 15);
            if (gc < N) {
#pragma unroll
                for (int e = 0; e < 4; ++e) {
                    const int gr = gr0 + e;
                    if (gr < M) part[zoff + (size_t)gr * N + gc] = acc[mi][ni][e];
                }
            }
        }
    }
}

// part[KS][.][N] summed + bias -> out (fp32)
__global__ __launch_bounds__(256) void reduce_bias(
    const float* __restrict__ part, const float* __restrict__ bias,
    float* __restrict__ out, int KS, int MN, int N)
{
    const int i4 = blockIdx.x * 256 + threadIdx.x;
    if (i4 * 4 >= MN) return;
    float4 s = make_float4(0.f, 0.f, 0.f, 0.f);
    for (int z = 0; z < KS; ++z) {
        const float4 p = *(const float4*)&part[(size_t)z * MN + i4 * 4];
        s.x += p.x; s.y += p.y; s.z += p.z; s.w += p.w;
    }
    const int col = (i4 * 4) % N;
    const float4 b = *(const float4*)&bias[col];
    s.x += b.x; s.y += b.y; s.z += b.z; s.w += b.w;
    *(float4*)&out[(size_t)i4 * 4] = s;
}

// IF neuron on raw input: x [T,B,F0] fp32 -> spikes bf16 bits
__global__ __launch_bounds__(256) void if0_kernel(
    const float* __restrict__ x, unsigned short* __restrict__ s)
{
    const size_t id = (size_t)blockIdx.x * blockDim.x + threadIdx.x;
    float v = 0.f;
#pragma unroll
    for (int t = 0; t < T_STEPS; ++t) {
        const size_t idx = (size_t)t * (BATCH * (size_t)F0) + id;
        v += x[idx];
        if (v >= 1.0f) { s[idx] = 0x3F80; v = 0.f; }
        else           { s[idx] = 0; }
    }
}

// Fused BN stats + BN apply + IF. Block = 64 features; stats bit-identical
// to the previous bn_stats (same 4-quarter summation order).
__global__ __launch_bounds__(256) void bn_stats_if(
    const float* __restrict__ z, const float* __restrict__ g,
    const float* __restrict__ be, unsigned short* __restrict__ s)
{
    __shared__ float ssum[4][64], ssq[4][64];
    __shared__ float ssc[64], ssh[64];
    const int l = threadIdx.x & 63;
    const int q = threadIdx.x >> 6;
    const int f = blockIdx.x * 64 + l;
    float sum = 0.f, sq = 0.f;
    for (int r = q; r < NROWS; r += 4) {
        const float v = z[(size_t)r * DIM + f];
        sum += v; sq += v * v;
    }
    ssum[q][l] = sum; ssq[q][l] = sq;
    __syncthreads();
    if (threadIdx.x < 64) {
        float ts = 0.f, tq = 0.f;
#pragma unroll
        for (int i = 0; i < 4; ++i) { ts += ssum[i][l]; tq += ssq[i][l]; }
        const float mean = ts * (1.0f / NROWS);
        const float var  = tq * (1.0f / NROWS) - mean * mean;
        const float inv  = rsqrtf(var + 1e-5f);
        const float sc   = g[f] * inv;
        ssc[l] = sc;
        ssh[l] = be[f] - mean * sc;
    }
    __syncthreads();
    const float sc = ssc[l];
    const float sh = ssh[l];
    for (int b = q; b < BATCH; b += 4) {
        const int id = b * DIM + f;
        float v = 0.f;
#pragma unroll
        for (int t = 0; t < T_STEPS; ++t) {
            const size_t idx = (size_t)t * (BATCH * DIM) + id;
            v += z[idx] * sc + sh;
            if (v >= 1.0f) { s[idx] = 0x3F80; v = 0.f; }
            else           { s[idx] = 0; }
        }
    }
}

// Layer-2 variant: emit only the T-mean of spikes (bf16, k/8 exact)
__global__ __launch_bounds__(256) void bn_stats_if_mean(
    const float* __restrict__ z, const float* __restrict__ g,
    const float* __restrict__ be, unsigned short* __restrict__ sbar)
{
    __shared__ float ssum[4][64], ssq[4][64];
    __shared__ float ssc[64], ssh[64];
    const int l = threadIdx.x & 63;
    const int q = threadIdx.x >> 6;
    const int f = blockIdx.x * 64 + l;
    float sum = 0.f, sq = 0.f;
    for (int r = q; r < NROWS; r += 4) {
        const float v = z[(size_t)r * DIM + f];
        sum += v; sq += v * v;
    }
    ssum[q][l] = sum; ssq[q][l] = sq;
    __syncthreads();
    if (threadIdx.x < 64) {
        float ts = 0.f, tq = 0.f;
#pragma unroll
        for (int i = 0; i < 4; ++i) { ts += ssum[i][l]; tq += ssq[i][l]; }
        const float mean = ts * (1.0f / NROWS);
        const float var  = tq * (1.0f / NROWS) - mean * mean;
        const float inv  = rsqrtf(var + 1e-5f);
        const float sc   = g[f] * inv;
        ssc[l] = sc;
        ssh[l] = be[f] - mean * sc;
    }
    __syncthreads();
    const float sc = ssc[l];
    const float sh = ssh[l];
    for (int b = q; b < BATCH; b += 4) {
        const int id = b * DIM + f;
        float v = 0.f;
        int cnt = 0;
#pragma unroll
        for (int t = 0; t < T_STEPS; ++t) {
            const size_t idx = (size_t)t * (BATCH * DIM) + id;
            v += z[idx] * sc + sh;
            if (v >= 1.0f) { cnt++; v = 0.f; }
        }
        sbar[id] = bf16_rne((float)cnt * 0.125f);
    }
}

extern "C" void kernel_launch(void* const* d_in, const int* in_sizes, int n_in,
                              void* d_out, int out_size, void* d_ws, size_t ws_size,
                              hipStream_t stream)
{
    const float* x    = (const float*)d_in[0];
    const float* W0   = (const float*)d_in[1];
    const float* b0   = (const float*)d_in[2];
    const float* g0   = (const float*)d_in[3];
    const float* be0  = (const float*)d_in[4];
    const float* W1   = (const float*)d_in[5];
    const float* b1   = (const float*)d_in[6];
    const float* g1   = (const float*)d_in[7];
    const float* be1  = (const float*)d_in[8];
    const float* W2   = (const float*)d_in[9];
    const float* b2   = (const float*)d_in[10];
    const float* g2   = (const float*)d_in[11];
    const float* be2  = (const float*)d_in[12];
    const float* Wout = (const float*)d_in[13];
    const float* bout = (const float*)d_in[14];
    float* out = (float*)d_out;
    (void)in_sizes; (void)n_in; (void)out_size; (void)ws_size;

    char* ws = (char*)d_ws;
    size_t off = 0;
    auto alloc = [&](size_t nbytes) {
        char* p = ws + off;
        off = (off + nbytes + 255) & ~(size_t)255;
        return p;
    };
    unsigned short* s0 = (unsigned short*)alloc((size_t)NROWS * F0 * 2);  // 33.5 MB
    unsigned short* s1 = (unsigned short*)alloc((size_t)NROWS * DIM * 2);
    unsigned short* s2 = (unsigned short*)alloc((size_t)NROWS * DIM * 2);
    unsigned short* sb = (unsigned short*)alloc((size_t)128 * DIM * 2);   // 128-row pad
    float* z    = (float*)alloc((size_t)NROWS * DIM * 4);
    float* part = (float*)alloc((size_t)16 * NROWS * DIM * 4);            // 67 MB (KS<=16)

    const int MN = NROWS * DIM;

    // sn0
    if0_kernel<<<(BATCH * (size_t)F0) / 256, 256, 0, stream>>>(x, s0);

    // layer 0: K=32768, KS=16  (grid 4*16*16=1024)
    gemm_splitk<<<dim3(NROWS / BM, DIM / BN, 16), 256, 0, stream>>>(
        s0, W0, part, NROWS, DIM, F0, F0 / 16, DIM);
    reduce_bias<<<MN / 4 / 256, 256, 0, stream>>>(part, b0, z, 16, MN, DIM);
    bn_stats_if<<<DIM / 64, 256, 0, stream>>>(z, g0, be0, s1);

    // layer 1: K=2048, KS=8  (grid 512)
    gemm_splitk<<<dim3(NROWS / BM, DIM / BN, 8), 256, 0, stream>>>(
        s1, W1, part, NROWS, DIM, DIM, DIM / 8, DIM);
    reduce_bias<<<MN / 4 / 256, 256, 0, stream>>>(part, b1, z, 8, MN, DIM);
    bn_stats_if<<<DIM / 64, 256, 0, stream>>>(z, g1, be1, s2);

    // layer 2: fused bn+if+T-mean
    gemm_splitk<<<dim3(NROWS / BM, DIM / BN, 8), 256, 0, stream>>>(
        s2, W2, part, NROWS, DIM, DIM, DIM / 8, DIM);
    reduce_bias<<<MN / 4 / 256, 256, 0, stream>>>(part, b2, z, 8, MN, DIM);
    bn_stats_if_mean<<<DIM / 64, 256, 0, stream>>>(z, g2, be2, sb);

    // readout: [64,2048] x [1000,2048]^T, KS=4 (grid 1*8*4=32)
    gemm_splitk<<<dim3(1, (NC + BN - 1) / BN, 4), 256, 0, stream>>>(
        sb, Wout, part, BATCH, NC, DIM, DIM / 4, NC);
    reduce_bias<<<(BATCH * NC / 4 + 255) / 256, 256, 0, stream>>>(
        part, bout, out, 4, BATCH * NC, NC);
}

// Round 9
// 472.707 us; speedup vs baseline: 1.0213x; 1.0213x over previous
//
#include <hip/hip_runtime.h>

// ---------------------------------------------------------------------------
// SpikingMLP forward. bf16 MFMA GEMMs, split-precision weights (W_hi+W_lo).
// R9: revert to R7's convert-in-staging (pure MFMA inner loop, proven
// 0-conflict 128B-row LDS geometry) + BK=32 double-buffered pipeline:
// issue loads(t+1) before MFMA(t), convert+write(t+1) after, 1 barrier/step.
// Accumulation order identical to R7 -> bit-identical spike trains.
// ---------------------------------------------------------------------------

#define T_STEPS 8
#define BATCH 64
#define F0 32768
#define DIM 2048
#define NROWS 512
#define NC 1000

typedef __attribute__((ext_vector_type(8))) short short8;   // 8 bf16
typedef __attribute__((ext_vector_type(4))) float f32x4;    // MFMA acc

__device__ __forceinline__ unsigned short bf16_rne(float f) {
    unsigned int u = __float_as_uint(f);
    u += 0x7FFFu + ((u >> 16) & 1u);
    return (unsigned short)(u >> 16);
}

#define BM 128
#define BN 128
#define BK 32   // A row = 64 B; HL row = 128 B ([32 hi bf16 | 32 lo bf16])

__global__ __launch_bounds__(256, 3) void gemm_splitk(
    const unsigned short* __restrict__ A, const float* __restrict__ W,
    float* __restrict__ part, int M, int N, int K, int Kpart, int Wrows)
{
    __shared__ unsigned short As[2][BM * BK];   // 2 x 8 KB bf16
    __shared__ unsigned short HL[2][BN * 64];   // 2 x 16 KB [hi|lo]

    // ---- XCD-chunked bijective remap (grid %8==0 at all call sites) ----
    const int gx = gridDim.x, gy = gridDim.y;
    const int nwg = gx * gy * gridDim.z;
    const int lid = blockIdx.x + gx * (blockIdx.y + gy * blockIdx.z);
    const int cpx = nwg >> 3;
    const int nid = (lid & 7) * cpx + (lid >> 3);
    const int bx  = nid % gx;
    const int by  = (nid / gx) % gy;
    const int kz  = nid / (gx * gy);

    const int tid  = threadIdx.x;
    const int lane = tid & 63;
    const int w    = tid >> 6;
    const int bm   = bx * BM;
    const int bn   = by * BN;
    const int ksteps = Kpart / BK;
    const int wm = (w >> 1) * 64;
    const int wn = (w & 1) * 64;
    const int kbase = kz * Kpart;

    // --- A staging (DMA): wave w, call c: rows w*32+c*16+(lane>>2), slot lane&3.
    // Swizzle: phys 16B-slot p of row r holds logical p ^ ((r>>1)&3).
    // Writer: logical = (lane&3) ^ ((lane>>3)&3)  [(row>>1)&3 = (lane>>3)&3]
    const int a_sl  = ((lane & 3) ^ ((lane >> 3) & 3)) << 4;
    const int a_row = lane >> 2;

    // --- W staging: thread loads 4x float4; row = (tid>>3)+32i, c4 = tid&7.
    // HL row 128B: hi half slots 0-3, lo half slots 4-7; phys = logical ^ (r&7).
    const int wn_row = tid >> 3;
    const int wc4    = tid & 7;
    const int r7     = wn_row & 7;
    const int hi_off = (((wc4 >> 1) ^ r7) << 4) + (wc4 & 1) * 8;
    const int lo_off = ((((wc4 >> 1) + 4) ^ r7) << 4) + (wc4 & 1) * 8;

    // --- fragment read offsets (R7-proven class: slot ^ (lane&7) on 128B rows)
    const int l15 = lane & 15;
    const int a_ph = (((lane >> 4) ^ ((l15 >> 1) & 3)) << 4);
    const int h_ph = (((lane >> 4) ^ (lane & 7)) << 4);
    const int l_ph = ((((lane >> 4) + 4) ^ (lane & 7)) << 4);

    f32x4 acc[4][4] = {};
    float4 wv[4];

    auto issue_loads = [&](int buf, int kt) {
        const int k0 = kbase + kt * BK;
        // W loads first (older in vmcnt queue than the A DMAs)
#pragma unroll
        for (int i = 0; i < 4; ++i) {
            const int rg = min(bn + wn_row + 32 * i, Wrows - 1);
            wv[i] = *(const float4*)&W[(size_t)rg * K + k0 + wc4 * 4];
        }
#pragma unroll
        for (int c = 0; c < 2; ++c) {
            const int row = w * 32 + c * 16 + a_row;
            const char* src = (const char*)A + ((size_t)(bm + row) * K + k0) * 2 + a_sl;
            __builtin_amdgcn_global_load_lds(
                (const __attribute__((address_space(1))) void*)src,
                (__attribute__((address_space(3))) void*)&As[buf][(w * 32 + c * 16) * BK],
                16, 0, 0);
        }
    };
    auto convert_write = [&](int buf) {
#pragma unroll
        for (int i = 0; i < 4; ++i) {
            const float vf[4] = {wv[i].x, wv[i].y, wv[i].z, wv[i].w};
            unsigned short h[4], l[4];
#pragma unroll
            for (int e = 0; e < 4; ++e) {
                h[e] = bf16_rne(vf[e]);
                l[e] = bf16_rne(vf[e] - __uint_as_float((unsigned int)h[e] << 16));
            }
            char* base = (char*)&HL[buf][0] + (wn_row + 32 * i) * 128;
            *(ushort4*)(base + hi_off) = make_ushort4(h[0], h[1], h[2], h[3]);
            *(ushort4*)(base + lo_off) = make_ushort4(l[0], l[1], l[2], l[3]);
        }
    };

    // prologue: stage tile 0
    issue_loads(0, 0);
    convert_write(0);
    __syncthreads();

    int cur = 0;
    for (int kt = 0; kt < ksteps; ++kt) {
        const bool last = (kt + 1 == ksteps);
        if (!last) issue_loads(cur ^ 1, kt + 1);   // W->regs + A->DMA, in flight

        short8 a[4];
#pragma unroll
        for (int mi = 0; mi < 4; ++mi)
            a[mi] = *(const short8*)((const char*)&As[cur][0] + (wm + mi * 16 + l15) * 64 + a_ph);
#pragma unroll
        for (int ni = 0; ni < 4; ++ni) {
            const char* rp = (const char*)&HL[cur][0] + (wn + ni * 16 + l15) * 128;
            const short8 bh = *(const short8*)(rp + h_ph);
            const short8 bl = *(const short8*)(rp + l_ph);
#pragma unroll
            for (int mi = 0; mi < 4; ++mi) {
                acc[mi][ni] = __builtin_amdgcn_mfma_f32_16x16x32_bf16(a[mi], bh, acc[mi][ni], 0, 0, 0);
                acc[mi][ni] = __builtin_amdgcn_mfma_f32_16x16x32_bf16(a[mi], bl, acc[mi][ni], 0, 0, 0);
            }
        }
        if (!last) convert_write(cur ^ 1);   // waits W regs (auto vmcnt), ds_write
        __syncthreads();                     // drains A DMA + ds_writes; frees cur
        cur ^= 1;
    }

    // ---- epilogue: partial store (C/D: col=lane&15, row=(lane>>4)*4+e) ----
    const size_t zoff = (size_t)kz * M * N;
#pragma unroll
    for (int mi = 0; mi < 4; ++mi) {
        const int gr0 = bm + wm + mi * 16 + (lane >> 4) * 4;
#pragma unroll
        for (int ni = 0; ni < 4; ++ni) {
            const int gc = bn + wn + ni * 16 + (lane & 15);
            if (gc < N) {
#pragma unroll
                for (int e = 0; e < 4; ++e) {
                    const int gr = gr0 + e;
                    if (gr < M) part[zoff + (size_t)gr * N + gc] = acc[mi][ni][e];
                }
            }
        }
    }
}

// part[KS][.][N] summed + bias -> out (fp32)
__global__ __launch_bounds__(256) void reduce_bias(
    const float* __restrict__ part, const float* __restrict__ bias,
    float* __restrict__ out, int KS, int MN, int N)
{
    const int i4 = blockIdx.x * 256 + threadIdx.x;
    if (i4 * 4 >= MN) return;
    float4 s = make_float4(0.f, 0.f, 0.f, 0.f);
    for (int z = 0; z < KS; ++z) {
        const float4 p = *(const float4*)&part[(size_t)z * MN + i4 * 4];
        s.x += p.x; s.y += p.y; s.z += p.z; s.w += p.w;
    }
    const int col = (i4 * 4) % N;
    const float4 b = *(const float4*)&bias[col];
    s.x += b.x; s.y += b.y; s.z += b.z; s.w += b.w;
    *(float4*)&out[(size_t)i4 * 4] = s;
}

// IF neuron on raw input, vectorized x4: x [T,B,F0] fp32 -> spikes bf16 bits
__global__ __launch_bounds__(256) void if0_kernel(
    const float* __restrict__ x, unsigned short* __restrict__ s)
{
    const size_t id4 = ((size_t)blockIdx.x * 256 + threadIdx.x) * 4;
    float v0 = 0.f, v1 = 0.f, v2 = 0.f, v3 = 0.f;
#pragma unroll
    for (int t = 0; t < T_STEPS; ++t) {
        const size_t idx = (size_t)t * (BATCH * (size_t)F0) + id4;
        const float4 xv = *(const float4*)&x[idx];
        ushort4 o;
        v0 += xv.x; if (v0 >= 1.f) { o.x = 0x3F80; v0 = 0.f; } else o.x = 0;
        v1 += xv.y; if (v1 >= 1.f) { o.y = 0x3F80; v1 = 0.f; } else o.y = 0;
        v2 += xv.z; if (v2 >= 1.f) { o.z = 0x3F80; v2 = 0.f; } else o.z = 0;
        v3 += xv.w; if (v3 >= 1.f) { o.w = 0x3F80; v3 = 0.f; } else o.w = 0;
        *(ushort4*)&s[idx] = o;
    }
}

// Fused BN stats + BN apply + IF (bit-identical stats order to R7/R8)
__global__ __launch_bounds__(256) void bn_stats_if(
    const float* __restrict__ z, const float* __restrict__ g,
    const float* __restrict__ be, unsigned short* __restrict__ s)
{
    __shared__ float ssum[4][64], ssq[4][64];
    __shared__ float ssc[64], ssh[64];
    const int l = threadIdx.x & 63;
    const int q = threadIdx.x >> 6;
    const int f = blockIdx.x * 64 + l;
    float sum = 0.f, sq = 0.f;
    for (int r = q; r < NROWS; r += 4) {
        const float v = z[(size_t)r * DIM + f];
        sum += v; sq += v * v;
    }
    ssum[q][l] = sum; ssq[q][l] = sq;
    __syncthreads();
    if (threadIdx.x < 64) {
        float ts = 0.f, tq = 0.f;
#pragma unroll
        for (int i = 0; i < 4; ++i) { ts += ssum[i][l]; tq += ssq[i][l]; }
        const float mean = ts * (1.0f / NROWS);
        const float var  = tq * (1.0f / NROWS) - mean * mean;
        const float inv  = rsqrtf(var + 1e-5f);
        const float sc   = g[f] * inv;
        ssc[l] = sc;
        ssh[l] = be[f] - mean * sc;
    }
    __syncthreads();
    const float sc = ssc[l];
    const float sh = ssh[l];
    for (int b = q; b < BATCH; b += 4) {
        const int id = b * DIM + f;
        float v = 0.f;
#pragma unroll
        for (int t = 0; t < T_STEPS; ++t) {
            const size_t idx = (size_t)t * (BATCH * DIM) + id;
            v += z[idx] * sc + sh;
            if (v >= 1.0f) { s[idx] = 0x3F80; v = 0.f; }
            else           { s[idx] = 0; }
        }
    }
}

// Layer-2 variant: emit only the T-mean of spikes (bf16, k/8 exact)
__global__ __launch_bounds__(256) void bn_stats_if_mean(
    const float* __restrict__ z, const float* __restrict__ g,
    const float* __restrict__ be, unsigned short* __restrict__ sbar)
{
    __shared__ float ssum[4][64], ssq[4][64];
    __shared__ float ssc[64], ssh[64];
    const int l = threadIdx.x & 63;
    const int q = threadIdx.x >> 6;
    const int f = blockIdx.x * 64 + l;
    float sum = 0.f, sq = 0.f;
    for (int r = q; r < NROWS; r += 4) {
        const float v = z[(size_t)r * DIM + f];
        sum += v; sq += v * v;
    }
    ssum[q][l] = sum; ssq[q][l] = sq;
    __syncthreads();
    if (threadIdx.x < 64) {
        float ts = 0.f, tq = 0.f;
#pragma unroll
        for (int i = 0; i < 4; ++i) { ts += ssum[i][l]; tq += ssq[i][l]; }
        const float mean = ts * (1.0f / NROWS);
        const float var  = tq * (1.0f / NROWS) - mean * mean;
        const float inv  = rsqrtf(var + 1e-5f);
        const float sc   = g[f] * inv;
        ssc[l] = sc;
        ssh[l] = be[f] - mean * sc;
    }
    __syncthreads();
    const float sc = ssc[l];
    const float sh = ssh[l];
    for (int b = q; b < BATCH; b += 4) {
        const int id = b * DIM + f;
        float v = 0.f;
        int cnt = 0;
#pragma unroll
        for (int t = 0; t < T_STEPS; ++t) {
            const size_t idx = (size_t)t * (BATCH * DIM) + id;
            v += z[idx] * sc + sh;
            if (v >= 1.0f) { cnt++; v = 0.f; }
        }
        sbar[id] = bf16_rne((float)cnt * 0.125f);
    }
}

extern "C" void kernel_launch(void* const* d_in, const int* in_sizes, int n_in,
                              void* d_out, int out_size, void* d_ws, size_t ws_size,
                              hipStream_t stream)
{
    const float* x    = (const float*)d_in[0];
    const float* W0   = (const float*)d_in[1];
    const float* b0   = (const float*)d_in[2];
    const float* g0   = (const float*)d_in[3];
    const float* be0  = (const float*)d_in[4];
    const float* W1   = (const float*)d_in[5];
    const float* b1   = (const float*)d_in[6];
    const float* g1   = (const float*)d_in[7];
    const float* be1  = (const float*)d_in[8];
    const float* W2   = (const float*)d_in[9];
    const float* b2   = (const float*)d_in[10];
    const float* g2   = (const float*)d_in[11];
    const float* be2  = (const float*)d_in[12];
    const float* Wout = (const float*)d_in[13];
    const float* bout = (const float*)d_in[14];
    float* out = (float*)d_out;
    (void)in_sizes; (void)n_in; (void)out_size; (void)ws_size;

    char* ws = (char*)d_ws;
    size_t off = 0;
    auto alloc = [&](size_t nbytes) {
        char* p = ws + off;
        off = (off + nbytes + 255) & ~(size_t)255;
        return p;
    };
    unsigned short* s0 = (unsigned short*)alloc((size_t)NROWS * F0 * 2);  // 33.5 MB
    unsigned short* s1 = (unsigned short*)alloc((size_t)NROWS * DIM * 2);
    unsigned short* s2 = (unsigned short*)alloc((size_t)NROWS * DIM * 2);
    unsigned short* sb = (unsigned short*)alloc((size_t)128 * DIM * 2);   // 128-row pad
    float* z    = (float*)alloc((size_t)NROWS * DIM * 4);
    float* part = (float*)alloc((size_t)16 * NROWS * DIM * 4);            // 67 MB (KS<=16)

    const int MN = NROWS * DIM;

    // sn0 (vectorized x4)
    if0_kernel<<<(BATCH * (size_t)F0) / 4 / 256, 256, 0, stream>>>(x, s0);

    // layer 0: K=32768, KS=16  (grid 4*16*16=1024)
    gemm_splitk<<<dim3(NROWS / BM, DIM / BN, 16), 256, 0, stream>>>(
        s0, W0, part, NROWS, DIM, F0, F0 / 16, DIM);
    reduce_bias<<<MN / 4 / 256, 256, 0, stream>>>(part, b0, z, 16, MN, DIM);
    bn_stats_if<<<DIM / 64, 256, 0, stream>>>(z, g0, be0, s1);

    // layer 1: K=2048, KS=8  (grid 512)
    gemm_splitk<<<dim3(NROWS / BM, DIM / BN, 8), 256, 0, stream>>>(
        s1, W1, part, NROWS, DIM, DIM, DIM / 8, DIM);
    reduce_bias<<<MN / 4 / 256, 256, 0, stream>>>(part, b1, z, 8, MN, DIM);
    bn_stats_if<<<DIM / 64, 256, 0, stream>>>(z, g1, be1, s2);

    // layer 2: fused bn+if+T-mean
    gemm_splitk<<<dim3(NROWS / BM, DIM / BN, 8), 256, 0, stream>>>(
        s2, W2, part, NROWS, DIM, DIM, DIM / 8, DIM);
    reduce_bias<<<MN / 4 / 256, 256, 0, stream>>>(part, b2, z, 8, MN, DIM);
    bn_stats_if_mean<<<DIM / 64, 256, 0, stream>>>(z, g2, be2, sb);

    // readout: [64,2048] x [1000,2048]^T, KS=4 (grid 1*8*4=32)
    gemm_splitk<<<dim3(1, (NC + BN - 1) / BN, 4), 256, 0, stream>>>(
        sb, Wout, part, BATCH, NC, DIM, DIM / 4, NC);
    reduce_bias<<<(BATCH * NC / 4 + 255) / 256, 256, 0, stream>>>(
        part, bout, out, 4, BATCH * NC, NC);
}

// Round 10
// 400.120 us; speedup vs baseline: 1.2066x; 1.1814x over previous
//
#include <hip/hip_runtime.h>

// ---------------------------------------------------------------------------
// SpikingMLP forward. bf16 MFMA GEMMs, split-precision weights (W_hi+W_lo,
// converted during staging — R7-proven zero-conflict LDS geometry, BK=64).
// R10: ONLY change vs R7 = 8 waves/block (512 thr), wave tile 64x32.
// Halves per-wave staging+MFMA phases; 3 blocks/CU = 24 waves/CU overlap.
// Accumulation order per output element identical to R7 -> same spikes.
// ---------------------------------------------------------------------------

#define T_STEPS 8
#define BATCH 64
#define F0 32768
#define DIM 2048
#define NROWS 512
#define NC 1000

typedef __attribute__((ext_vector_type(8))) short short8;   // 8 bf16
typedef __attribute__((ext_vector_type(4))) float f32x4;    // MFMA acc

__device__ __forceinline__ unsigned short bf16_rne(float f) {
    unsigned int u = __float_as_uint(f);
    u += 0x7FFFu + ((u >> 16) & 1u);
    return (unsigned short)(u >> 16);
}

#define BM 128
#define BN 128
#define BK 64

__device__ __forceinline__ short8 lds_frag(const unsigned short* base, int row, int kb) {
    const int off = row * 128 + (kb ^ ((row & 7) << 4));
    return *(const short8*)((const char*)base + off);
}

__global__ __launch_bounds__(512) void gemm_splitk(
    const unsigned short* __restrict__ A, const float* __restrict__ W,
    float* __restrict__ part, int M, int N, int K, int Kpart, int Wrows)
{
    __shared__ unsigned short As[BM * BK];   // 16 KB
    __shared__ unsigned short Hs[BN * BK];   // 16 KB (W hi)
    __shared__ unsigned short Ls[BN * BK];   // 16 KB (W lo)

    // ---- XCD-chunked bijective remap (grid %8==0 at all call sites) ----
    const int gx = gridDim.x, gy = gridDim.y;
    const int nwg = gx * gy * gridDim.z;
    const int lid = blockIdx.x + gx * (blockIdx.y + gy * blockIdx.z);
    const int cpx = nwg >> 3;
    const int nid = (lid & 7) * cpx + (lid >> 3);
    const int bx  = nid % gx;
    const int by  = (nid / gx) % gy;
    const int kz  = nid / (gx * gy);

    const int tid  = threadIdx.x;
    const int lane = tid & 63;
    const int w    = tid >> 6;          // 0..7
    const int bm   = bx * BM;
    const int bn   = by * BN;
    const int ksteps = Kpart / BK;
    const int wm = (w >> 2) * 64;       // 2 M-halves
    const int wn = (w & 3) * 32;        // 4 N-quarters

    f32x4 acc[4][2] = {};

    for (int kt = 0; kt < ksteps; ++kt) {
        const int k0 = kz * Kpart + kt * BK;

        // ---- A tile: global_load_lds, linear dst + XOR'd src (R7 geometry) ----
#pragma unroll
        for (int c = 0; c < 2; ++c) {
            const int r    = w * 16 + c * 8 + (lane >> 3);
            const int colb = ((lane & 7) * 16) ^ ((r & 7) << 4);
            const char* src = (const char*)A + ((size_t)(bm + r) * K + k0) * 2 + colb;
            unsigned short* dst = &As[(w * 16 + c * 8) * BK];
            __builtin_amdgcn_global_load_lds(
                (const __attribute__((address_space(1))) void*)src,
                (__attribute__((address_space(3))) void*)dst, 16, 0, 0);
        }

        // ---- W tile: fp32 loads -> hi/lo bf16 split -> swizzled ds_write ----
        float4 wv[4];
#pragma unroll
        for (int i = 0; i < 4; ++i) {
            const int q  = tid + 512 * i;
            const int n  = q >> 4;
            const int c4 = q & 15;
            const int gn = min(bn + n, Wrows - 1);
            wv[i] = *(const float4*)&W[(size_t)gn * K + k0 + c4 * 4];
        }
#pragma unroll
        for (int i = 0; i < 4; ++i) {
            const int q  = tid + 512 * i;
            const int n  = q >> 4;
            const int c4 = q & 15;
            const float vf[4] = {wv[i].x, wv[i].y, wv[i].z, wv[i].w};
            unsigned short h[4], l[4];
#pragma unroll
            for (int e = 0; e < 4; ++e) {
                h[e] = bf16_rne(vf[e]);
                const float hf = __uint_as_float((unsigned int)h[e] << 16);
                l[e] = bf16_rne(vf[e] - hf);
            }
            const int off = n * 128 + ((c4 * 8) ^ ((n & 7) << 4));
            *(ushort4*)((char*)Hs + off) = make_ushort4(h[0], h[1], h[2], h[3]);
            *(ushort4*)((char*)Ls + off) = make_ushort4(l[0], l[1], l[2], l[3]);
        }

        __syncthreads();   // drains vmcnt (A dma) + lgkmcnt (W ds_writes)

        // ---- MFMA: acc += A*Whi + A*Wlo (pure LDS->MFMA) ----
#pragma unroll
        for (int kk = 0; kk < 2; ++kk) {
            const int kb = (kk * 32 + (lane >> 4) * 8) * 2;
            short8 a[4], bh[2], bl[2];
#pragma unroll
            for (int i = 0; i < 4; ++i)
                a[i] = lds_frag(As, wm + i * 16 + (lane & 15), kb);
#pragma unroll
            for (int i = 0; i < 2; ++i) {
                const int r = wn + i * 16 + (lane & 15);
                bh[i] = lds_frag(Hs, r, kb);
                bl[i] = lds_frag(Ls, r, kb);
            }
#pragma unroll
            for (int mi = 0; mi < 4; ++mi)
#pragma unroll
                for (int ni = 0; ni < 2; ++ni) {
                    acc[mi][ni] = __builtin_amdgcn_mfma_f32_16x16x32_bf16(
                        a[mi], bh[ni], acc[mi][ni], 0, 0, 0);
                    acc[mi][ni] = __builtin_amdgcn_mfma_f32_16x16x32_bf16(
                        a[mi], bl[ni], acc[mi][ni], 0, 0, 0);
                }
        }
        __syncthreads();
    }

    // ---- epilogue: partial store (C/D: col=lane&15, row=(lane>>4)*4+e) ----
    const size_t zoff = (size_t)kz * M * N;
#pragma unroll
    for (int mi = 0; mi < 4; ++mi) {
        const int gr0 = bm + wm + mi * 16 + (lane >> 4) * 4;
#pragma unroll
        for (int ni = 0; ni < 2; ++ni) {
            const int gc = bn + wn + ni * 16 + (lane & 15);
            if (gc < N) {
#pragma unroll
                for (int e = 0; e < 4; ++e) {
                    const int gr = gr0 + e;
                    if (gr < M) part[zoff + (size_t)gr * N + gc] = acc[mi][ni][e];
                }
            }
        }
    }
}

// part[KS][.][N] summed + bias -> out (fp32)
__global__ __launch_bounds__(256) void reduce_bias(
    const float* __restrict__ part, const float* __restrict__ bias,
    float* __restrict__ out, int KS, int MN, int N)
{
    const int i4 = blockIdx.x * 256 + threadIdx.x;
    if (i4 * 4 >= MN) return;
    float4 s = make_float4(0.f, 0.f, 0.f, 0.f);
    for (int z = 0; z < KS; ++z) {
        const float4 p = *(const float4*)&part[(size_t)z * MN + i4 * 4];
        s.x += p.x; s.y += p.y; s.z += p.z; s.w += p.w;
    }
    const int col = (i4 * 4) % N;
    const float4 b = *(const float4*)&bias[col];
    s.x += b.x; s.y += b.y; s.z += b.z; s.w += b.w;
    *(float4*)&out[(size_t)i4 * 4] = s;
}

// IF neuron on raw input, vectorized x4: x [T,B,F0] fp32 -> spikes bf16 bits
__global__ __launch_bounds__(256) void if0_kernel(
    const float* __restrict__ x, unsigned short* __restrict__ s)
{
    const size_t id4 = ((size_t)blockIdx.x * 256 + threadIdx.x) * 4;
    float v0 = 0.f, v1 = 0.f, v2 = 0.f, v3 = 0.f;
#pragma unroll
    for (int t = 0; t < T_STEPS; ++t) {
        const size_t idx = (size_t)t * (BATCH * (size_t)F0) + id4;
        const float4 xv = *(const float4*)&x[idx];
        ushort4 o;
        v0 += xv.x; if (v0 >= 1.f) { o.x = 0x3F80; v0 = 0.f; } else o.x = 0;
        v1 += xv.y; if (v1 >= 1.f) { o.y = 0x3F80; v1 = 0.f; } else o.y = 0;
        v2 += xv.z; if (v2 >= 1.f) { o.z = 0x3F80; v2 = 0.f; } else o.z = 0;
        v3 += xv.w; if (v3 >= 1.f) { o.w = 0x3F80; v3 = 0.f; } else o.w = 0;
        *(ushort4*)&s[idx] = o;
    }
}

// Fused BN stats + BN apply + IF (stats order identical to R7's bn_stats)
__global__ __launch_bounds__(256) void bn_stats_if(
    const float* __restrict__ z, const float* __restrict__ g,
    const float* __restrict__ be, unsigned short* __restrict__ s)
{
    __shared__ float ssum[4][64], ssq[4][64];
    __shared__ float ssc[64], ssh[64];
    const int l = threadIdx.x & 63;
    const int q = threadIdx.x >> 6;
    const int f = blockIdx.x * 64 + l;
    float sum = 0.f, sq = 0.f;
    for (int r = q; r < NROWS; r += 4) {
        const float v = z[(size_t)r * DIM + f];
        sum += v; sq += v * v;
    }
    ssum[q][l] = sum; ssq[q][l] = sq;
    __syncthreads();
    if (threadIdx.x < 64) {
        float ts = 0.f, tq = 0.f;
#pragma unroll
        for (int i = 0; i < 4; ++i) { ts += ssum[i][l]; tq += ssq[i][l]; }
        const float mean = ts * (1.0f / NROWS);
        const float var  = tq * (1.0f / NROWS) - mean * mean;
        const float inv  = rsqrtf(var + 1e-5f);
        const float sc   = g[f] * inv;
        ssc[l] = sc;
        ssh[l] = be[f] - mean * sc;
    }
    __syncthreads();
    const float sc = ssc[l];
    const float sh = ssh[l];
    for (int b = q; b < BATCH; b += 4) {
        const int id = b * DIM + f;
        float v = 0.f;
#pragma unroll
        for (int t = 0; t < T_STEPS; ++t) {
            const size_t idx = (size_t)t * (BATCH * DIM) + id;
            v += z[idx] * sc + sh;
            if (v >= 1.0f) { s[idx] = 0x3F80; v = 0.f; }
            else           { s[idx] = 0; }
        }
    }
}

// Layer-2 variant: emit only the T-mean of spikes (bf16, k/8 exact)
__global__ __launch_bounds__(256) void bn_stats_if_mean(
    const float* __restrict__ z, const float* __restrict__ g,
    const float* __restrict__ be, unsigned short* __restrict__ sbar)
{
    __shared__ float ssum[4][64], ssq[4][64];
    __shared__ float ssc[64], ssh[64];
    const int l = threadIdx.x & 63;
    const int q = threadIdx.x >> 6;
    const int f = blockIdx.x * 64 + l;
    float sum = 0.f, sq = 0.f;
    for (int r = q; r < NROWS; r += 4) {
        const float v = z[(size_t)r * DIM + f];
        sum += v; sq += v * v;
    }
    ssum[q][l] = sum; ssq[q][l] = sq;
    __syncthreads();
    if (threadIdx.x < 64) {
        float ts = 0.f, tq = 0.f;
#pragma unroll
        for (int i = 0; i < 4; ++i) { ts += ssum[i][l]; tq += ssq[i][l]; }
        const float mean = ts * (1.0f / NROWS);
        const float var  = tq * (1.0f / NROWS) - mean * mean;
        const float inv  = rsqrtf(var + 1e-5f);
        const float sc   = g[f] * inv;
        ssc[l] = sc;
        ssh[l] = be[f] - mean * sc;
    }
    __syncthreads();
    const float sc = ssc[l];
    const float sh = ssh[l];
    for (int b = q; b < BATCH; b += 4) {
        const int id = b * DIM + f;
        float v = 0.f;
        int cnt = 0;
#pragma unroll
        for (int t = 0; t < T_STEPS; ++t) {
            const size_t idx = (size_t)t * (BATCH * DIM) + id;
            v += z[idx] * sc + sh;
            if (v >= 1.0f) { cnt++; v = 0.f; }
        }
        sbar[id] = bf16_rne((float)cnt * 0.125f);
    }
}

extern "C" void kernel_launch(void* const* d_in, const int* in_sizes, int n_in,
                              void* d_out, int out_size, void* d_ws, size_t ws_size,
                              hipStream_t stream)
{
    const float* x    = (const float*)d_in[0];
    const float* W0   = (const float*)d_in[1];
    const float* b0   = (const float*)d_in[2];
    const float* g0   = (const float*)d_in[3];
    const float* be0  = (const float*)d_in[4];
    const float* W1   = (const float*)d_in[5];
    const float* b1   = (const float*)d_in[6];
    const float* g1   = (const float*)d_in[7];
    const float* be1  = (const float*)d_in[8];
    const float* W2   = (const float*)d_in[9];
    const float* b2   = (const float*)d_in[10];
    const float* g2   = (const float*)d_in[11];
    const float* be2  = (const float*)d_in[12];
    const float* Wout = (const float*)d_in[13];
    const float* bout = (const float*)d_in[14];
    float* out = (float*)d_out;
    (void)in_sizes; (void)n_in; (void)out_size; (void)ws_size;

    char* ws = (char*)d_ws;
    size_t off = 0;
    auto alloc = [&](size_t nbytes) {
        char* p = ws + off;
        off = (off + nbytes + 255) & ~(size_t)255;
        return p;
    };
    unsigned short* s0 = (unsigned short*)alloc((size_t)NROWS * F0 * 2);  // 33.5 MB
    unsigned short* s1 = (unsigned short*)alloc((size_t)NROWS * DIM * 2);
    unsigned short* s2 = (unsigned short*)alloc((size_t)NROWS * DIM * 2);
    unsigned short* sb = (unsigned short*)alloc((size_t)128 * DIM * 2);   // 128-row pad
    float* z    = (float*)alloc((size_t)NROWS * DIM * 4);
    float* part = (float*)alloc((size_t)16 * NROWS * DIM * 4);            // 67 MB (KS<=16)

    const int MN = NROWS * DIM;

    // sn0 (vectorized x4)
    if0_kernel<<<(BATCH * (size_t)F0) / 4 / 256, 256, 0, stream>>>(x, s0);

    // layer 0: K=32768, KS=16  (grid 4*16*16=1024)
    gemm_splitk<<<dim3(NROWS / BM, DIM / BN, 16), 512, 0, stream>>>(
        s0, W0, part, NROWS, DIM, F0, F0 / 16, DIM);
    reduce_bias<<<MN / 4 / 256, 256, 0, stream>>>(part, b0, z, 16, MN, DIM);
    bn_stats_if<<<DIM / 64, 256, 0, stream>>>(z, g0, be0, s1);

    // layer 1: K=2048, KS=8  (grid 512)
    gemm_splitk<<<dim3(NROWS / BM, DIM / BN, 8), 512, 0, stream>>>(
        s1, W1, part, NROWS, DIM, DIM, DIM / 8, DIM);
    reduce_bias<<<MN / 4 / 256, 256, 0, stream>>>(part, b1, z, 8, MN, DIM);
    bn_stats_if<<<DIM / 64, 256, 0, stream>>>(z, g1, be1, s2);

    // layer 2: fused bn+if+T-mean
    gemm_splitk<<<dim3(NROWS / BM, DIM / BN, 8), 512, 0, stream>>>(
        s2, W2, part, NROWS, DIM, DIM, DIM / 8, DIM);
    reduce_bias<<<MN / 4 / 256, 256, 0, stream>>>(part, b2, z, 8, MN, DIM);
    bn_stats_if_mean<<<DIM / 64, 256, 0, stream>>>(z, g2, be2, sb);

    // readout: [64,2048] x [1000,2048]^T, KS=4 (grid 1*8*4=32)
    gemm_splitk<<<dim3(1, (NC + BN - 1) / BN, 4), 512, 0, stream>>>(
        sb, Wout, part, BATCH, NC, DIM, DIM / 4, NC);
    reduce_bias<<<(BATCH * NC / 4 + 255) / 256, 256, 0, stream>>>(
        part, bout, out, 4, BATCH * NC, NC);
}

// Round 11
// 395.084 us; speedup vs baseline: 1.2219x; 1.0127x over previous
//
#include <hip/hip_runtime.h>

// ---------------------------------------------------------------------------
// SpikingMLP forward. bf16 MFMA GEMMs, split-precision weights (W_hi+W_lo,
// converted during staging — R7/R10 measured-zero-conflict LDS geometry).
// R11: in-block pipeline with raw barriers. A dbuf in LDS via global_load_lds;
// W(t+1) prefetched to regs BEFORE MFMA(t); convert+ds_write AFTER raw
// s_barrier (no vmcnt(0) drain of prefetch). 64 KB LDS -> 2 blocks/CU.
// Per-acc accumulation order unchanged (kt asc, kk asc, hi then lo).
// ---------------------------------------------------------------------------

#define T_STEPS 8
#define BATCH 64
#define F0 32768
#define DIM 2048
#define NROWS 512
#define NC 1000

typedef __attribute__((ext_vector_type(8))) short short8;   // 8 bf16
typedef __attribute__((ext_vector_type(4))) float f32x4;    // MFMA acc

__device__ __forceinline__ unsigned short bf16_rne(float f) {
    unsigned int u = __float_as_uint(f);
    u += 0x7FFFu + ((u >> 16) & 1u);
    return (unsigned short)(u >> 16);
}

#define BM 128
#define BN 128
#define BK 64

#define SBAR() do { __builtin_amdgcn_sched_barrier(0); \
                    __builtin_amdgcn_s_barrier();      \
                    __builtin_amdgcn_sched_barrier(0); } while (0)

__device__ __forceinline__ short8 lds_frag(const unsigned short* base, int row, int kb) {
    const int off = row * 128 + (kb ^ ((row & 7) << 4));
    return *(const short8*)((const char*)base + off);
}

__global__ __launch_bounds__(512) void gemm_splitk(
    const unsigned short* __restrict__ A, const float* __restrict__ W,
    float* __restrict__ part, int M, int N, int K, int Kpart, int Wrows)
{
    __shared__ unsigned short As[2][BM * BK];   // 2 x 16 KB (A dbuf)
    __shared__ unsigned short Hs[BN * BK];      // 16 KB (W hi)
    __shared__ unsigned short Ls[BN * BK];      // 16 KB (W lo)

    // ---- XCD-chunked bijective remap (grid %8==0 at all call sites) ----
    const int gx = gridDim.x, gy = gridDim.y;
    const int nwg = gx * gy * gridDim.z;
    const int lid = blockIdx.x + gx * (blockIdx.y + gy * blockIdx.z);
    const int cpx = nwg >> 3;
    const int nid = (lid & 7) * cpx + (lid >> 3);
    const int bx  = nid % gx;
    const int by  = (nid / gx) % gy;
    const int kz  = nid / (gx * gy);

    const int tid  = threadIdx.x;
    const int lane = tid & 63;
    const int w    = tid >> 6;          // 0..7
    const int bm   = bx * BM;
    const int bn   = by * BN;
    const int ksteps = Kpart / BK;
    const int wm = (w >> 2) * 64;
    const int wn = (w & 3) * 32;
    const int kbase = kz * Kpart;

    f32x4 acc[4][2] = {};
    float4 wv[4];

    // W-loads FIRST, then A-DMA: convert's register wait becomes a counted
    // vmcnt (A-DMAs remain outstanding under MFMA).
    auto issue_loads = [&](int buf, int kt) {
        const int k0 = kbase + kt * BK;
#pragma unroll
        for (int i = 0; i < 4; ++i) {
            const int n  = (tid >> 4) + 32 * i;
            const int c4 = tid & 15;
            const int gn = min(bn + n, Wrows - 1);
            wv[i] = *(const float4*)&W[(size_t)gn * K + k0 + c4 * 4];
        }
#pragma unroll
        for (int c = 0; c < 2; ++c) {
            const int r    = w * 16 + c * 8 + (lane >> 3);
            const int colb = ((lane & 7) * 16) ^ ((r & 7) << 4);
            const char* src = (const char*)A + ((size_t)(bm + r) * K + k0) * 2 + colb;
            unsigned short* dst = &As[buf][(w * 16 + c * 8) * BK];
            __builtin_amdgcn_global_load_lds(
                (const __attribute__((address_space(1))) void*)src,
                (__attribute__((address_space(3))) void*)dst, 16, 0, 0);
        }
    };

    auto convert_write = [&]() {
#pragma unroll
        for (int i = 0; i < 4; ++i) {
            const int n  = (tid >> 4) + 32 * i;
            const int c4 = tid & 15;
            const float vf[4] = {wv[i].x, wv[i].y, wv[i].z, wv[i].w};
            unsigned short h[4], l[4];
#pragma unroll
            for (int e = 0; e < 4; ++e) {
                h[e] = bf16_rne(vf[e]);
                const float hf = __uint_as_float((unsigned int)h[e] << 16);
                l[e] = bf16_rne(vf[e] - hf);
            }
            const int off = n * 128 + ((c4 * 8) ^ ((n & 7) << 4));
            *(ushort4*)((char*)Hs + off) = make_ushort4(h[0], h[1], h[2], h[3]);
            *(ushort4*)((char*)Ls + off) = make_ushort4(l[0], l[1], l[2], l[3]);
        }
    };

    // prologue: stage tile 0 fully
    issue_loads(0, 0);
    convert_write();
    asm volatile("s_waitcnt vmcnt(0) lgkmcnt(0)" ::: "memory");
    SBAR();

    int cur = 0;
    for (int kt = 0; kt < ksteps; ++kt) {
        const bool last = (kt + 1 == ksteps);
        if (!last) issue_loads(cur ^ 1, kt + 1);   // W->regs + A-DMA, in flight

        // ---- MFMA phase: pure LDS->MFMA on As[cur], Hs, Ls ----
#pragma unroll
        for (int kk = 0; kk < 2; ++kk) {
            const int kb = (kk * 32 + (lane >> 4) * 8) * 2;
            short8 a[4], bh[2], bl[2];
#pragma unroll
            for (int i = 0; i < 4; ++i)
                a[i] = lds_frag(&As[cur][0], wm + i * 16 + (lane & 15), kb);
#pragma unroll
            for (int i = 0; i < 2; ++i) {
                const int r = wn + i * 16 + (lane & 15);
                bh[i] = lds_frag(Hs, r, kb);
                bl[i] = lds_frag(Ls, r, kb);
            }
#pragma unroll
            for (int mi = 0; mi < 4; ++mi)
#pragma unroll
                for (int ni = 0; ni < 2; ++ni) {
                    acc[mi][ni] = __builtin_amdgcn_mfma_f32_16x16x32_bf16(
                        a[mi], bh[ni], acc[mi][ni], 0, 0, 0);
                    acc[mi][ni] = __builtin_amdgcn_mfma_f32_16x16x32_bf16(
                        a[mi], bl[ni], acc[mi][ni], 0, 0, 0);
                }
        }

        if (!last) {
            SBAR();            // all waves done reading Hs/Ls(t) (data in regs)
            convert_write();   // counted vmcnt wait on W regs; Hs/Ls(t+1)
            asm volatile("s_waitcnt vmcnt(0) lgkmcnt(0)" ::: "memory"); // A-DMA + ds_writes
            SBAR();            // As[cur^1] + Hs/Ls(t+1) visible to all
            cur ^= 1;
        }
    }

    // ---- epilogue: partial store (C/D: col=lane&15, row=(lane>>4)*4+e) ----
    const size_t zoff = (size_t)kz * M * N;
#pragma unroll
    for (int mi = 0; mi < 4; ++mi) {
        const int gr0 = bm + wm + mi * 16 + (lane >> 4) * 4;
#pragma unroll
        for (int ni = 0; ni < 2; ++ni) {
            const int gc = bn + wn + ni * 16 + (lane & 15);
            if (gc < N) {
#pragma unroll
                for (int e = 0; e < 4; ++e) {
                    const int gr = gr0 + e;
                    if (gr < M) part[zoff + (size_t)gr * N + gc] = acc[mi][ni][e];
                }
            }
        }
    }
}

// part[KS][.][N] summed + bias -> out (fp32)
__global__ __launch_bounds__(256) void reduce_bias(
    const float* __restrict__ part, const float* __restrict__ bias,
    float* __restrict__ out, int KS, int MN, int N)
{
    const int i4 = blockIdx.x * 256 + threadIdx.x;
    if (i4 * 4 >= MN) return;
    float4 s = make_float4(0.f, 0.f, 0.f, 0.f);
    for (int z = 0; z < KS; ++z) {
        const float4 p = *(const float4*)&part[(size_t)z * MN + i4 * 4];
        s.x += p.x; s.y += p.y; s.z += p.z; s.w += p.w;
    }
    const int col = (i4 * 4) % N;
    const float4 b = *(const float4*)&bias[col];
    s.x += b.x; s.y += b.y; s.z += b.z; s.w += b.w;
    *(float4*)&out[(size_t)i4 * 4] = s;
}

// IF neuron on raw input, vectorized x4
__global__ __launch_bounds__(256) void if0_kernel(
    const float* __restrict__ x, unsigned short* __restrict__ s)
{
    const size_t id4 = ((size_t)blockIdx.x * 256 + threadIdx.x) * 4;
    float v0 = 0.f, v1 = 0.f, v2 = 0.f, v3 = 0.f;
#pragma unroll
    for (int t = 0; t < T_STEPS; ++t) {
        const size_t idx = (size_t)t * (BATCH * (size_t)F0) + id4;
        const float4 xv = *(const float4*)&x[idx];
        ushort4 o;
        v0 += xv.x; if (v0 >= 1.f) { o.x = 0x3F80; v0 = 0.f; } else o.x = 0;
        v1 += xv.y; if (v1 >= 1.f) { o.y = 0x3F80; v1 = 0.f; } else o.y = 0;
        v2 += xv.z; if (v2 >= 1.f) { o.z = 0x3F80; v2 = 0.f; } else o.z = 0;
        v3 += xv.w; if (v3 >= 1.f) { o.w = 0x3F80; v3 = 0.f; } else o.w = 0;
        *(ushort4*)&s[idx] = o;
    }
}

// Fused BN stats + BN apply + IF (stats order unchanged)
__global__ __launch_bounds__(256) void bn_stats_if(
    const float* __restrict__ z, const float* __restrict__ g,
    const float* __restrict__ be, unsigned short* __restrict__ s)
{
    __shared__ float ssum[4][64], ssq[4][64];
    __shared__ float ssc[64], ssh[64];
    const int l = threadIdx.x & 63;
    const int q = threadIdx.x >> 6;
    const int f = blockIdx.x * 64 + l;
    float sum = 0.f, sq = 0.f;
    for (int r = q; r < NROWS; r += 4) {
        const float v = z[(size_t)r * DIM + f];
        sum += v; sq += v * v;
    }
    ssum[q][l] = sum; ssq[q][l] = sq;
    __syncthreads();
    if (threadIdx.x < 64) {
        float ts = 0.f, tq = 0.f;
#pragma unroll
        for (int i = 0; i < 4; ++i) { ts += ssum[i][l]; tq += ssq[i][l]; }
        const float mean = ts * (1.0f / NROWS);
        const float var  = tq * (1.0f / NROWS) - mean * mean;
        const float inv  = rsqrtf(var + 1e-5f);
        const float sc   = g[f] * inv;
        ssc[l] = sc;
        ssh[l] = be[f] - mean * sc;
    }
    __syncthreads();
    const float sc = ssc[l];
    const float sh = ssh[l];
    for (int b = q; b < BATCH; b += 4) {
        const int id = b * DIM + f;
        float v = 0.f;
#pragma unroll
        for (int t = 0; t < T_STEPS; ++t) {
            const size_t idx = (size_t)t * (BATCH * DIM) + id;
            v += z[idx] * sc + sh;
            if (v >= 1.0f) { s[idx] = 0x3F80; v = 0.f; }
            else           { s[idx] = 0; }
        }
    }
}

// Layer-2 variant: emit only the T-mean of spikes (bf16, k/8 exact)
__global__ __launch_bounds__(256) void bn_stats_if_mean(
    const float* __restrict__ z, const float* __restrict__ g,
    const float* __restrict__ be, unsigned short* __restrict__ sbar)
{
    __shared__ float ssum[4][64], ssq[4][64];
    __shared__ float ssc[64], ssh[64];
    const int l = threadIdx.x & 63;
    const int q = threadIdx.x >> 6;
    const int f = blockIdx.x * 64 + l;
    float sum = 0.f, sq = 0.f;
    for (int r = q; r < NROWS; r += 4) {
        const float v = z[(size_t)r * DIM + f];
        sum += v; sq += v * v;
    }
    ssum[q][l] = sum; ssq[q][l] = sq;
    __syncthreads();
    if (threadIdx.x < 64) {
        float ts = 0.f, tq = 0.f;
#pragma unroll
        for (int i = 0; i < 4; ++i) { ts += ssum[i][l]; tq += ssq[i][l]; }
        const float mean = ts * (1.0f / NROWS);
        const float var  = tq * (1.0f / NROWS) - mean * mean;
        const float inv  = rsqrtf(var + 1e-5f);
        const float sc   = g[f] * inv;
        ssc[l] = sc;
        ssh[l] = be[f] - mean * sc;
    }
    __syncthreads();
    const float sc = ssc[l];
    const float sh = ssh[l];
    for (int b = q; b < BATCH; b += 4) {
        const int id = b * DIM + f;
        float v = 0.f;
        int cnt = 0;
#pragma unroll
        for (int t = 0; t < T_STEPS; ++t) {
            const size_t idx = (size_t)t * (BATCH * DIM) + id;
            v += z[idx] * sc + sh;
            if (v >= 1.0f) { cnt++; v = 0.f; }
        }
        sbar[id] = bf16_rne((float)cnt * 0.125f);
    }
}

extern "C" void kernel_launch(void* const* d_in, const int* in_sizes, int n_in,
                              void* d_out, int out_size, void* d_ws, size_t ws_size,
                              hipStream_t stream)
{
    const float* x    = (const float*)d_in[0];
    const float* W0   = (const float*)d_in[1];
    const float* b0   = (const float*)d_in[2];
    const float* g0   = (const float*)d_in[3];
    const float* be0  = (const float*)d_in[4];
    const float* W1   = (const float*)d_in[5];
    const float* b1   = (const float*)d_in[6];
    const float* g1   = (const float*)d_in[7];
    const float* be1  = (const float*)d_in[8];
    const float* W2   = (const float*)d_in[9];
    const float* b2   = (const float*)d_in[10];
    const float* g2   = (const float*)d_in[11];
    const float* be2  = (const float*)d_in[12];
    const float* Wout = (const float*)d_in[13];
    const float* bout = (const float*)d_in[14];
    float* out = (float*)d_out;
    (void)in_sizes; (void)n_in; (void)out_size; (void)ws_size;

    char* ws = (char*)d_ws;
    size_t off = 0;
    auto alloc = [&](size_t nbytes) {
        char* p = ws + off;
        off = (off + nbytes + 255) & ~(size_t)255;
        return p;
    };
    unsigned short* s0 = (unsigned short*)alloc((size_t)NROWS * F0 * 2);  // 33.5 MB
    unsigned short* s1 = (unsigned short*)alloc((size_t)NROWS * DIM * 2);
    unsigned short* s2 = (unsigned short*)alloc((size_t)NROWS * DIM * 2);
    unsigned short* sb = (unsigned short*)alloc((size_t)128 * DIM * 2);   // 128-row pad
    float* z    = (float*)alloc((size_t)NROWS * DIM * 4);
    float* part = (float*)alloc((size_t)16 * NROWS * DIM * 4);            // 67 MB

    const int MN = NROWS * DIM;

    // sn0 (vectorized x4)
    if0_kernel<<<(BATCH * (size_t)F0) / 4 / 256, 256, 0, stream>>>(x, s0);

    // layer 0: K=32768, KS=8  (grid 4*16*8=512 = exactly 2 blocks/CU)
    gemm_splitk<<<dim3(NROWS / BM, DIM / BN, 8), 512, 0, stream>>>(
        s0, W0, part, NROWS, DIM, F0, F0 / 8, DIM);
    reduce_bias<<<MN / 4 / 256, 256, 0, stream>>>(part, b0, z, 8, MN, DIM);
    bn_stats_if<<<DIM / 64, 256, 0, stream>>>(z, g0, be0, s1);

    // layer 1: K=2048, KS=8  (grid 512)
    gemm_splitk<<<dim3(NROWS / BM, DIM / BN, 8), 512, 0, stream>>>(
        s1, W1, part, NROWS, DIM, DIM, DIM / 8, DIM);
    reduce_bias<<<MN / 4 / 256, 256, 0, stream>>>(part, b1, z, 8, MN, DIM);
    bn_stats_if<<<DIM / 64, 256, 0, stream>>>(z, g1, be1, s2);

    // layer 2: fused bn+if+T-mean
    gemm_splitk<<<dim3(NROWS / BM, DIM / BN, 8), 512, 0, stream>>>(
        s2, W2, part, NROWS, DIM, DIM, DIM / 8, DIM);
    reduce_bias<<<MN / 4 / 256, 256, 0, stream>>>(part, b2, z, 8, MN, DIM);
    bn_stats_if_mean<<<DIM / 64, 256, 0, stream>>>(z, g2, be2, sb);

    // readout: [64,2048] x [1000,2048]^T, KS=8 (grid 1*8*8=64)
    gemm_splitk<<<dim3(1, (NC + BN - 1) / BN, 8), 512, 0, stream>>>(
        sb, Wout, part, BATCH, NC, DIM, DIM / 8, NC);
    reduce_bias<<<(BATCH * NC / 4 + 255) / 256, 256, 0, stream>>>(
        part, bout, out, 8, BATCH * NC, NC);
}